// Round 1
// baseline (532.103 us; speedup 1.0000x reference)
//
#include <hip/hip_runtime.h>
#include <hip/hip_bf16.h>
#include <cstddef>

// Shapes (fixed by the problem)
#define BB 8
#define TT 512
#define CC 512
#define NHH 8
#define HDD 64
// M = B*T = 4096, K = 512, N_qkv = 1536

// ---------------------------------------------------------------------------
// Kernel 1: qkv = x @ w_attn^T + b_attn
//   x [4096,512], w [1536,512]. q,k -> qkbuf[4096][1024]; v -> Vh[B][NH][T][HD]
//   Tile 128(M) x 64(N), BK=8, 256 threads, 8x4 micro-tile, reg prefetch.
// ---------------------------------------------------------------------------
__global__ __launch_bounds__(256) void gemm_qkv_k(
    const float* __restrict__ x, const float* __restrict__ w,
    const float* __restrict__ bias, float* __restrict__ qkbuf,
    float* __restrict__ Vh)
{
    __shared__ float As[8][132];
    __shared__ float Bs[8][68];
    const int tid = threadIdx.x;
    const int bm = blockIdx.y * 128;
    const int bn = blockIdx.x * 64;
    const int tx = tid & 15;   // n: tx*4
    const int ty = tid >> 4;   // m: ty*8

    float acc[8][4];
#pragma unroll
    for (int i = 0; i < 8; ++i)
#pragma unroll
        for (int j = 0; j < 4; ++j) acc[i][j] = 0.f;

    const int lrow = tid >> 1;          // 0..127
    const int lk = (tid & 1) * 4;       // 0 or 4
    const float* xa = x + (size_t)(bm + lrow) * 512 + lk;
    const bool doB = tid < 128;
    const float* wa = w + (size_t)(bn + (lrow & 63)) * 512 + lk;

    float4 av = *(const float4*)xa;
    float4 bv = make_float4(0.f, 0.f, 0.f, 0.f);
    if (doB) bv = *(const float4*)wa;

    for (int k0 = 0; k0 < 512; k0 += 8) {
        __syncthreads();
        As[lk + 0][lrow] = av.x; As[lk + 1][lrow] = av.y;
        As[lk + 2][lrow] = av.z; As[lk + 3][lrow] = av.w;
        if (doB) {
            Bs[lk + 0][lrow] = bv.x; Bs[lk + 1][lrow] = bv.y;
            Bs[lk + 2][lrow] = bv.z; Bs[lk + 3][lrow] = bv.w;
        }
        __syncthreads();
        if (k0 + 8 < 512) {
            av = *(const float4*)(xa + k0 + 8);
            if (doB) bv = *(const float4*)(wa + k0 + 8);
        }
#pragma unroll
        for (int kk = 0; kk < 8; ++kk) {
            const float4 a0 = *(const float4*)&As[kk][ty * 8];
            const float4 a1 = *(const float4*)&As[kk][ty * 8 + 4];
            const float4 b0 = *(const float4*)&Bs[kk][tx * 4];
            const float am[8] = {a0.x, a0.y, a0.z, a0.w, a1.x, a1.y, a1.z, a1.w};
            const float bb[4] = {b0.x, b0.y, b0.z, b0.w};
#pragma unroll
            for (int i = 0; i < 8; ++i)
#pragma unroll
                for (int j = 0; j < 4; ++j) acc[i][j] += am[i] * bb[j];
        }
    }

    const int n = bn + tx * 4;
    const float4 bb4 = *(const float4*)(bias + n);
    if (bn < 1024) {
        // q or k stream -> qkbuf[m][n], row stride 1024
#pragma unroll
        for (int i = 0; i < 8; ++i) {
            const int m = bm + ty * 8 + i;
            const float4 o = make_float4(acc[i][0] + bb4.x, acc[i][1] + bb4.y,
                                         acc[i][2] + bb4.z, acc[i][3] + bb4.w);
            *(float4*)(qkbuf + (size_t)m * 1024 + n) = o;
        }
    } else {
        // v stream -> Vh[b][h][t][d]
        const int hd = n - 1024;
        const int h = hd >> 6, d = hd & 63;
#pragma unroll
        for (int i = 0; i < 8; ++i) {
            const int m = bm + ty * 8 + i;
            const int bi = m >> 9, t = m & 511;
            const float4 o = make_float4(acc[i][0] + bb4.x, acc[i][1] + bb4.y,
                                         acc[i][2] + bb4.z, acc[i][3] + bb4.w);
            *(float4*)(Vh + (((size_t)bi * NHH + h) * TT + t) * HDD + d) = o;
        }
    }
}

// ---------------------------------------------------------------------------
// Kernel 2: in-place LayerNorm over C=512 on q (cols 0..511) and k (512..1023)
//   One block per (b,t) row of qkbuf. 256 threads, 2 elems/thread/stream.
// ---------------------------------------------------------------------------
__global__ __launch_bounds__(256) void ln_k(
    float* __restrict__ qkbuf,
    const float* __restrict__ qg, const float* __restrict__ qb,
    const float* __restrict__ kg, const float* __restrict__ kb)
{
    const int row = blockIdx.x;
    float* base = qkbuf + (size_t)row * 1024;
    const int tid = threadIdx.x;
    __shared__ float red[8];
    __shared__ float stat[2];

#pragma unroll
    for (int s = 0; s < 2; ++s) {
        float* p = base + s * 512;
        const float* gam = s ? kg : qg;
        const float* bet = s ? kb : qb;
        const float v0 = p[tid];
        const float v1 = p[tid + 256];
        float sum = v0 + v1;
        float sq = v0 * v0 + v1 * v1;
#pragma unroll
        for (int off = 32; off > 0; off >>= 1) {
            sum += __shfl_down(sum, off);
            sq += __shfl_down(sq, off);
        }
        const int lane = tid & 63, wv = tid >> 6;
        if (lane == 0) { red[wv * 2] = sum; red[wv * 2 + 1] = sq; }
        __syncthreads();
        if (tid == 0) {
            const float ts = red[0] + red[2] + red[4] + red[6];
            const float tq = red[1] + red[3] + red[5] + red[7];
            const float mu = ts * (1.f / 512.f);
            const float var = tq * (1.f / 512.f) - mu * mu;
            stat[0] = mu;
            stat[1] = rsqrtf(var + 1e-5f);
        }
        __syncthreads();
        const float mu = stat[0], rs = stat[1];
        p[tid]       = (v0 - mu) * rs * gam[tid] + bet[tid];
        p[tid + 256] = (v1 - mu) * rs * gam[tid + 256] + bet[tid + 256];
        __syncthreads();  // red/stat reused by next stream
    }
}

// ---------------------------------------------------------------------------
// Kernel 3: flash-style causal attention with relative-position bias.
//   Block = (q-tile 64, head, batch), 256 threads: row r = tid>>2 (64 rows),
//   group g = tid&3 owns 16 score cols and 16 output dims.
//   s[i][j] = 0.125 * q_i . (k_j + rel_emb[i-j, h*64:]) for j<=i.
//   Rel rows staged per k-tile: window index r - jc + 63 in [0,126].
// ---------------------------------------------------------------------------
__global__ __launch_bounds__(256) void attn_k(
    const float* __restrict__ qkbuf, const float* __restrict__ Vh,
    const float* __restrict__ rel, float* __restrict__ Yh)
{
    __shared__ float Qs[64][68];
    __shared__ float Ks[64][68];
    __shared__ float Vs[64][64];
    __shared__ float Rs[128][68];
    __shared__ float Ps[64][65];

    const int tid = threadIdx.x;
    const int qt = blockIdx.x;   // 0..7
    const int h = blockIdx.y;    // 0..7
    const int b = blockIdx.z;    // 0..7
    const int i0 = qt * 64;

    const float* Qbase = qkbuf + (size_t)b * TT * 1024 + h * 64;
    const float* Kbase = Qbase + 512;
    const float* Vbase = Vh + ((size_t)(b * NHH + h)) * TT * HDD;
    const float* Rbase = rel + h * 64;

    // stage Q tile (64 x 64)
#pragma unroll
    for (int l = 0; l < 4; ++l) {
        const int idx = l * 256 + tid;
        const int row = idx >> 4;
        const int c4 = (idx & 15) << 2;
        *(float4*)&Qs[row][c4] = *(const float4*)(Qbase + (size_t)(i0 + row) * 1024 + c4);
    }

    const int r = tid >> 2;
    const int g = tid & 3;
    const int i_glob = i0 + r;

    float m_i = -1e30f, l_i = 0.f;
    float O[16];
#pragma unroll
    for (int d = 0; d < 16; ++d) O[d] = 0.f;

    for (int jt = 0; jt <= qt; ++jt) {
        const int j0 = jt * 64;
        // stage K, V tiles
#pragma unroll
        for (int l = 0; l < 4; ++l) {
            const int idx = l * 256 + tid;
            const int row = idx >> 4;
            const int c4 = (idx & 15) << 2;
            *(float4*)&Ks[row][c4] = *(const float4*)(Kbase + (size_t)(j0 + row) * 1024 + c4);
            *(float4*)&Vs[row][c4] = *(const float4*)(Vbase + (size_t)(j0 + row) * 64 + c4);
        }
        // stage rel window: m = i0-j0-63+rr, clamped (clamped rows only feed masked scores)
        const int mbase = i0 - j0 - 63;
#pragma unroll
        for (int l = 0; l < 8; ++l) {
            const int idx = l * 256 + tid;
            const int rr = idx >> 4;
            const int c4 = (idx & 15) << 2;
            int m = mbase + rr;
            m = m < 0 ? 0 : (m > 511 ? 511 : m);
            *(float4*)&Rs[rr][c4] = *(const float4*)(Rbase + (size_t)m * 512 + c4);
        }
        __syncthreads();

        // scores -> Ps (raw, masked), track row max
        const float4* Q4 = (const float4*)&Qs[r][0];
        float tmax = -1e30f;
#pragma unroll 2
        for (int jj = 0; jj < 16; ++jj) {
            const int jc = g * 16 + jj;
            const float4* K4 = (const float4*)&Ks[jc][0];
            const float4* R4 = (const float4*)&Rs[r - jc + 63][0];
            float a0 = 0.f, a1 = 0.f, a2 = 0.f, a3 = 0.f;
#pragma unroll
            for (int d4 = 0; d4 < 16; ++d4) {
                const float4 q = Q4[d4];
                const float4 k = K4[d4];
                const float4 rv = R4[d4];
                a0 += q.x * (k.x + rv.x);
                a1 += q.y * (k.y + rv.y);
                a2 += q.z * (k.z + rv.z);
                a3 += q.w * (k.w + rv.w);
            }
            float s = ((a0 + a1) + (a2 + a3)) * 0.125f;
            s = (j0 + jc > i_glob) ? -1e30f : s;
            Ps[r][jc] = s;
            tmax = fmaxf(tmax, s);
        }
        tmax = fmaxf(tmax, __shfl_xor(tmax, 1));
        tmax = fmaxf(tmax, __shfl_xor(tmax, 2));
        const float m_new = fmaxf(m_i, tmax);
        float psum = 0.f;
#pragma unroll 4
        for (int jj = 0; jj < 16; ++jj) {
            const int jc = g * 16 + jj;
            const float p = __expf(Ps[r][jc] - m_new);
            Ps[r][jc] = p;
            psum += p;
        }
        psum += __shfl_xor(psum, 1);
        psum += __shfl_xor(psum, 2);
        const float alpha = __expf(m_i - m_new);
        l_i = l_i * alpha + psum;
        m_i = m_new;
#pragma unroll
        for (int d = 0; d < 16; ++d) O[d] *= alpha;
        __syncthreads();   // Ps visible to all 4 g-threads of each row

        // O += P @ V  (this thread: output dims g*16 .. g*16+15)
#pragma unroll 4
        for (int jc = 0; jc < 64; ++jc) {
            const float pv = Ps[r][jc];
            const float4* V4 = (const float4*)&Vs[jc][g * 16];
            const float4 v0 = V4[0], v1 = V4[1], v2 = V4[2], v3 = V4[3];
            O[0]  += pv * v0.x; O[1]  += pv * v0.y; O[2]  += pv * v0.z; O[3]  += pv * v0.w;
            O[4]  += pv * v1.x; O[5]  += pv * v1.y; O[6]  += pv * v1.z; O[7]  += pv * v1.w;
            O[8]  += pv * v2.x; O[9]  += pv * v2.y; O[10] += pv * v2.z; O[11] += pv * v2.w;
            O[12] += pv * v3.x; O[13] += pv * v3.y; O[14] += pv * v3.z; O[15] += pv * v3.w;
        }
        __syncthreads();   // Ks/Vs/Rs/Ps reused next tile
    }

    const float inv = 1.f / l_i;
    float* yb = Yh + ((size_t)b * TT + i_glob) * CC + h * 64 + g * 16;
    *(float4*)(yb + 0)  = make_float4(O[0] * inv,  O[1] * inv,  O[2] * inv,  O[3] * inv);
    *(float4*)(yb + 4)  = make_float4(O[4] * inv,  O[5] * inv,  O[6] * inv,  O[7] * inv);
    *(float4*)(yb + 8)  = make_float4(O[8] * inv,  O[9] * inv,  O[10] * inv, O[11] * inv);
    *(float4*)(yb + 12) = make_float4(O[12] * inv, O[13] * inv, O[14] * inv, O[15] * inv);
}

// ---------------------------------------------------------------------------
// Kernel 4: out = Yh @ w_proj^T + b_proj   (M=4096, N=512, K=512)
//   Tile 64x64, BK=16, 256 threads, 4x4 micro-tile, reg prefetch.
// ---------------------------------------------------------------------------
__global__ __launch_bounds__(256) void gemm_proj_k(
    const float* __restrict__ y, const float* __restrict__ w,
    const float* __restrict__ bias, float* __restrict__ out)
{
    __shared__ float As[16][68];
    __shared__ float Bs[16][68];
    const int tid = threadIdx.x;
    const int bm = blockIdx.y * 64;
    const int bn = blockIdx.x * 64;
    const int tx = tid & 15, ty = tid >> 4;

    float acc[4][4];
#pragma unroll
    for (int i = 0; i < 4; ++i)
#pragma unroll
        for (int j = 0; j < 4; ++j) acc[i][j] = 0.f;

    const int lrow = tid >> 2;        // 0..63
    const int lk = (tid & 3) * 4;     // 0,4,8,12
    const float* ya = y + (size_t)(bm + lrow) * 512 + lk;
    const float* wa = w + (size_t)(bn + lrow) * 512 + lk;
    float4 av = *(const float4*)ya;
    float4 bv = *(const float4*)wa;

    for (int k0 = 0; k0 < 512; k0 += 16) {
        __syncthreads();
        As[lk + 0][lrow] = av.x; As[lk + 1][lrow] = av.y;
        As[lk + 2][lrow] = av.z; As[lk + 3][lrow] = av.w;
        Bs[lk + 0][lrow] = bv.x; Bs[lk + 1][lrow] = bv.y;
        Bs[lk + 2][lrow] = bv.z; Bs[lk + 3][lrow] = bv.w;
        __syncthreads();
        if (k0 + 16 < 512) {
            av = *(const float4*)(ya + k0 + 16);
            bv = *(const float4*)(wa + k0 + 16);
        }
#pragma unroll
        for (int kk = 0; kk < 16; ++kk) {
            const float4 a = *(const float4*)&As[kk][ty * 4];
            const float4 b = *(const float4*)&Bs[kk][tx * 4];
            const float am[4] = {a.x, a.y, a.z, a.w};
            const float bb[4] = {b.x, b.y, b.z, b.w};
#pragma unroll
            for (int i = 0; i < 4; ++i)
#pragma unroll
                for (int j = 0; j < 4; ++j) acc[i][j] += am[i] * bb[j];
        }
    }

    const int n = bn + tx * 4;
    const float4 bb4 = *(const float4*)(bias + n);
#pragma unroll
    for (int i = 0; i < 4; ++i) {
        const int m = bm + ty * 4 + i;
        const float4 o = make_float4(acc[i][0] + bb4.x, acc[i][1] + bb4.y,
                                     acc[i][2] + bb4.z, acc[i][3] + bb4.w);
        *(float4*)(out + (size_t)m * 512 + n) = o;
    }
}

// ---------------------------------------------------------------------------
extern "C" void kernel_launch(void* const* d_in, const int* in_sizes, int n_in,
                              void* d_out, int out_size, void* d_ws, size_t ws_size,
                              hipStream_t stream)
{
    const float* x      = (const float*)d_in[0];
    const float* w_attn = (const float*)d_in[1];
    const float* b_attn = (const float*)d_in[2];
    const float* w_proj = (const float*)d_in[3];
    const float* b_proj = (const float*)d_in[4];
    const float* q_g    = (const float*)d_in[5];
    const float* q_b    = (const float*)d_in[6];
    const float* k_g    = (const float*)d_in[7];
    const float* k_b    = (const float*)d_in[8];
    const float* rel    = (const float*)d_in[9];
    float* out = (float*)d_out;

    // workspace layout (floats): qk [4096*1024] | Vh [2M] | Yh [2M]  = 32 MiB
    float* qkbuf = (float*)d_ws;
    float* Vh = qkbuf + (size_t)4096 * 1024;
    float* Yh = Vh + (size_t)BB * NHH * TT * HDD;

    gemm_qkv_k<<<dim3(24, 32), 256, 0, stream>>>(x, w_attn, b_attn, qkbuf, Vh);
    ln_k<<<4096, 256, 0, stream>>>(qkbuf, q_g, q_b, k_g, k_b);
    attn_k<<<dim3(8, 8, 8), 256, 0, stream>>>(qkbuf, Vh, rel, Yh);
    gemm_proj_k<<<dim3(8, 64), 256, 0, stream>>>(Yh, w_proj, b_proj, out);
}

// Round 2
// 239.237 us; speedup vs baseline: 2.2242x; 2.2242x over previous
//
#include <hip/hip_runtime.h>
#include <hip/hip_bf16.h>
#include <cstddef>

// Shapes (fixed by the problem)
#define BB 8
#define TT 512
#define CC 512
#define NHH 8
#define HDD 64
// M = B*T = 4096, K = 512, N_qkv = 1536

typedef __attribute__((ext_vector_type(8))) short short8;
typedef __attribute__((ext_vector_type(4))) float f32x4;

__device__ __forceinline__ unsigned short f2bf(float f) {
    unsigned u = __float_as_uint(f);
    u += 0x7FFFu + ((u >> 16) & 1u);
    return (unsigned short)(u >> 16);
}
__device__ __forceinline__ float bf2f(unsigned short h) {
    return __uint_as_float(((unsigned)h) << 16);
}

// ---------------------------------------------------------------------------
// Kernel 0: rel (fp32 [512,512]) -> Relb (bf16)
// ---------------------------------------------------------------------------
__global__ __launch_bounds__(256) void cvt_rel_k(
    const float* __restrict__ in, unsigned short* __restrict__ out)
{
    const int i = (blockIdx.x * 256 + threadIdx.x) * 4;
    const float4 v = *(const float4*)(in + i);
    unsigned short tmp[4] = {f2bf(v.x), f2bf(v.y), f2bf(v.z), f2bf(v.w)};
    *(uint2*)(out + i) = *(const uint2*)tmp;
}

// ---------------------------------------------------------------------------
// Kernel 1: qkv = x @ w_attn^T + b_attn   (fp32 math, proven in round 1)
//   q,k -> qkbuf[4096][1024] fp32; v -> VT[B][NH][HD][T] bf16 (transposed!)
// ---------------------------------------------------------------------------
__global__ __launch_bounds__(256) void gemm_qkv_k(
    const float* __restrict__ x, const float* __restrict__ w,
    const float* __restrict__ bias, float* __restrict__ qkbuf,
    unsigned short* __restrict__ VT)
{
    __shared__ float As[8][132];
    __shared__ float Bs[8][68];
    const int tid = threadIdx.x;
    const int bm = blockIdx.y * 128;
    const int bn = blockIdx.x * 64;
    const int tx = tid & 15;   // n: tx*4
    const int ty = tid >> 4;   // m: ty*8

    float acc[8][4];
#pragma unroll
    for (int i = 0; i < 8; ++i)
#pragma unroll
        for (int j = 0; j < 4; ++j) acc[i][j] = 0.f;

    const int lrow = tid >> 1;          // 0..127
    const int lk = (tid & 1) * 4;       // 0 or 4
    const float* xa = x + (size_t)(bm + lrow) * 512 + lk;
    const bool doB = tid < 128;
    const float* wa = w + (size_t)(bn + (lrow & 63)) * 512 + lk;

    float4 av = *(const float4*)xa;
    float4 bv = make_float4(0.f, 0.f, 0.f, 0.f);
    if (doB) bv = *(const float4*)wa;

    for (int k0 = 0; k0 < 512; k0 += 8) {
        __syncthreads();
        As[lk + 0][lrow] = av.x; As[lk + 1][lrow] = av.y;
        As[lk + 2][lrow] = av.z; As[lk + 3][lrow] = av.w;
        if (doB) {
            Bs[lk + 0][lrow] = bv.x; Bs[lk + 1][lrow] = bv.y;
            Bs[lk + 2][lrow] = bv.z; Bs[lk + 3][lrow] = bv.w;
        }
        __syncthreads();
        if (k0 + 8 < 512) {
            av = *(const float4*)(xa + k0 + 8);
            if (doB) bv = *(const float4*)(wa + k0 + 8);
        }
#pragma unroll
        for (int kk = 0; kk < 8; ++kk) {
            const float4 a0 = *(const float4*)&As[kk][ty * 8];
            const float4 a1 = *(const float4*)&As[kk][ty * 8 + 4];
            const float4 b0 = *(const float4*)&Bs[kk][tx * 4];
            const float am[8] = {a0.x, a0.y, a0.z, a0.w, a1.x, a1.y, a1.z, a1.w};
            const float bb[4] = {b0.x, b0.y, b0.z, b0.w};
#pragma unroll
            for (int i = 0; i < 8; ++i)
#pragma unroll
                for (int j = 0; j < 4; ++j) acc[i][j] += am[i] * bb[j];
        }
    }

    const int n = bn + tx * 4;
    const float4 bb4 = *(const float4*)(bias + n);
    if (bn < 1024) {
#pragma unroll
        for (int i = 0; i < 8; ++i) {
            const int m = bm + ty * 8 + i;
            const float4 o = make_float4(acc[i][0] + bb4.x, acc[i][1] + bb4.y,
                                         acc[i][2] + bb4.z, acc[i][3] + bb4.w);
            *(float4*)(qkbuf + (size_t)m * 1024 + n) = o;
        }
    } else {
        // v stream -> VT[b][h][d][t] bf16; thread's 8 m-rows are 8 consecutive t
        const int hd = n - 1024;
        const int h = hd >> 6, d0 = hd & 63;
        const int m0 = bm + ty * 8;
        const int bi = m0 >> 9, t0 = m0 & 511;
        const float badd[4] = {bb4.x, bb4.y, bb4.z, bb4.w};
#pragma unroll
        for (int j = 0; j < 4; ++j) {
            unsigned short tmp[8];
#pragma unroll
            for (int i = 0; i < 8; ++i) tmp[i] = f2bf(acc[i][j] + badd[j]);
            *(short8*)(VT + ((size_t)(bi * NHH + h) * HDD + d0 + j) * TT + t0) =
                *(const short8*)tmp;
        }
    }
}

// ---------------------------------------------------------------------------
// Kernel 2: LayerNorm over C=512 on q and k; outputs bf16 head-major
//   Qh/Kh [B][NH][T][HD]. One block per (b,t) row.
// ---------------------------------------------------------------------------
__global__ __launch_bounds__(256) void ln_k(
    const float* __restrict__ qkbuf,
    const float* __restrict__ qg, const float* __restrict__ qb,
    const float* __restrict__ kg, const float* __restrict__ kb,
    unsigned short* __restrict__ Qh, unsigned short* __restrict__ Kh)
{
    const int row = blockIdx.x;
    const int bi = row >> 9, t = row & 511;
    const float* base = qkbuf + (size_t)row * 1024;
    const int tid = threadIdx.x;
    __shared__ float red[8];
    __shared__ float stat[2];

#pragma unroll
    for (int sstr = 0; sstr < 2; ++sstr) {
        const float* p = base + sstr * 512;
        const float* gam = sstr ? kg : qg;
        const float* bet = sstr ? kb : qb;
        unsigned short* outp = sstr ? Kh : Qh;
        const float v0 = p[tid];
        const float v1 = p[tid + 256];
        float sum = v0 + v1;
        float sq = v0 * v0 + v1 * v1;
#pragma unroll
        for (int off = 32; off > 0; off >>= 1) {
            sum += __shfl_down(sum, off);
            sq += __shfl_down(sq, off);
        }
        const int lane = tid & 63, wv = tid >> 6;
        if (lane == 0) { red[wv * 2] = sum; red[wv * 2 + 1] = sq; }
        __syncthreads();
        if (tid == 0) {
            const float ts = red[0] + red[2] + red[4] + red[6];
            const float tq = red[1] + red[3] + red[5] + red[7];
            const float mu = ts * (1.f / 512.f);
            const float var = tq * (1.f / 512.f) - mu * mu;
            stat[0] = mu;
            stat[1] = rsqrtf(var + 1e-5f);
        }
        __syncthreads();
        const float mu = stat[0], rsg = stat[1];
        const float o0 = (v0 - mu) * rsg * gam[tid] + bet[tid];
        const float o1 = (v1 - mu) * rsg * gam[tid + 256] + bet[tid + 256];
        const int c0 = tid, c1 = tid + 256;
        outp[((size_t)(bi * NHH + (c0 >> 6)) * TT + t) * HDD + (c0 & 63)] = f2bf(o0);
        outp[((size_t)(bi * NHH + (c1 >> 6)) * TT + t) * HDD + (c1 & 63)] = f2bf(o1);
        __syncthreads();
    }
}

// ---------------------------------------------------------------------------
// Kernel 3: MFMA flash attention with relative-position bias.
//   Block = (qt, h, b), 256 thr = 4 waves; wave w owns q-rows [w*16, w*16+16).
//   Per k-tile: S = Q@K^T (MFMA), RD[r][d'] = Q@RelWin^T (MFMA),
//   S[r][jc] += RD[r][r-jc+63] (LDS gather), online softmax, O += P@V (MFMA).
//   All operand tiles staged in fragment order: lane L's 8 bf16 at base+L*16B,
//   element = Mat[n16*16 + (L&15)][kk*32 + (L>>4)*8 + j]  -> conflict-free b128.
// ---------------------------------------------------------------------------
__global__ __launch_bounds__(256, 2) void attn_k(
    const unsigned short* __restrict__ Qh, const unsigned short* __restrict__ Kh,
    const unsigned short* __restrict__ VT, const unsigned short* __restrict__ Relb,
    float* __restrict__ Yh)
{
    __shared__ __align__(16) unsigned short Qs[8 * 512];    // 8 1KB chunks
    __shared__ __align__(16) unsigned short Ks[8 * 512];
    __shared__ __align__(16) unsigned short Vs[8 * 512];
    __shared__ __align__(16) unsigned short Rels[16 * 512]; // 127-row rel window
    __shared__ __align__(16) unsigned short Ps[4][16 * 72];  // per-wave P, stride 72
    __shared__ __align__(16) unsigned short RDs[4][16 * 132];// per-wave RD, stride 132

    const int tid = threadIdx.x;
    const int w = tid >> 6;
    const int lane = tid & 63;
    const int c = lane & 15;
    const int quad = lane >> 4;
    const int qt = blockIdx.x, h = blockIdx.y, b = blockIdx.z;
    const int i0 = qt * 64;

    const unsigned short* Qbase = Qh + (size_t)(b * NHH + h) * TT * HDD;
    const unsigned short* Kbase = Kh + (size_t)(b * NHH + h) * TT * HDD;
    const unsigned short* Vbase = VT + (size_t)(b * NHH + h) * HDD * TT;
    const unsigned short* Rbase = Relb + h * HDD;   // row stride CC

    // stage Q fragments once: chunk (w, kk)
#pragma unroll
    for (int kk = 0; kk < 2; ++kk) {
        const unsigned short* gp =
            Qbase + (size_t)(i0 + w * 16 + c) * HDD + kk * 32 + quad * 8;
        *(short8*)&Qs[(w * 2 + kk) * 512 + lane * 8] = *(const short8*)gp;
    }

    f32x4 oacc[4];
    float m_i[4], l_i[4];
#pragma unroll
    for (int r = 0; r < 4; ++r) { m_i[r] = -1e30f; l_i[r] = 0.f; }
#pragma unroll
    for (int nd = 0; nd < 4; ++nd) oacc[nd] = (f32x4){0.f, 0.f, 0.f, 0.f};

    short8 aq0, aq1;

    for (int jt = 0; jt <= qt; ++jt) {
        const int j0 = jt * 64;
        // stage K tile: chunk (j16=w, kk)
#pragma unroll
        for (int kk = 0; kk < 2; ++kk) {
            const unsigned short* gp =
                Kbase + (size_t)(j0 + w * 16 + c) * HDD + kk * 32 + quad * 8;
            *(short8*)&Ks[(w * 2 + kk) * 512 + lane * 8] = *(const short8*)gp;
        }
        // stage V tile (from VT): chunk (d16=w, jstep)
#pragma unroll
        for (int js = 0; js < 2; ++js) {
            const unsigned short* gp =
                Vbase + (size_t)(w * 16 + c) * TT + j0 + js * 32 + quad * 8;
            *(short8*)&Vs[(w * 2 + js) * 512 + lane * 8] = *(const short8*)gp;
        }
        // stage rel window rows mbase..mbase+127 (only d' in [0,126] ever used)
        const int mbase = i0 - j0 - 63;
#pragma unroll
        for (int sb = 0; sb < 2; ++sb) {
#pragma unroll
            for (int kk = 0; kk < 2; ++kk) {
                const int n16 = w * 2 + sb;
                int mrow = mbase + n16 * 16 + c;
                mrow = mrow < 0 ? 0 : (mrow > 511 ? 511 : mrow);
                const unsigned short* gp =
                    Rbase + (size_t)mrow * CC + kk * 32 + quad * 8;
                *(short8*)&Rels[(n16 * 2 + kk) * 512 + lane * 8] = *(const short8*)gp;
            }
        }
        __syncthreads();

        if (jt == 0) {
            aq0 = *(const short8*)&Qs[(w * 2 + 0) * 512 + lane * 8];
            aq1 = *(const short8*)&Qs[(w * 2 + 1) * 512 + lane * 8];
        }

        // S = Q @ K^T : 4 n-subtiles x 2 k-steps
        f32x4 sAcc[4];
#pragma unroll
        for (int ns = 0; ns < 4; ++ns) {
            const short8 bk0 = *(const short8*)&Ks[(ns * 2 + 0) * 512 + lane * 8];
            const short8 bk1 = *(const short8*)&Ks[(ns * 2 + 1) * 512 + lane * 8];
            f32x4 acc = (f32x4){0.f, 0.f, 0.f, 0.f};
            acc = __builtin_amdgcn_mfma_f32_16x16x32_bf16(aq0, bk0, acc, 0, 0, 0);
            acc = __builtin_amdgcn_mfma_f32_16x16x32_bf16(aq1, bk1, acc, 0, 0, 0);
            sAcc[ns] = acc;
        }
        // RD = Q @ RelWin^T : 8 n-subtiles, dump to per-wave LDS (bf16)
#pragma unroll
        for (int nr = 0; nr < 8; ++nr) {
            const short8 br0 = *(const short8*)&Rels[(nr * 2 + 0) * 512 + lane * 8];
            const short8 br1 = *(const short8*)&Rels[(nr * 2 + 1) * 512 + lane * 8];
            f32x4 acc = (f32x4){0.f, 0.f, 0.f, 0.f};
            acc = __builtin_amdgcn_mfma_f32_16x16x32_bf16(aq0, br0, acc, 0, 0, 0);
            acc = __builtin_amdgcn_mfma_f32_16x16x32_bf16(aq1, br1, acc, 0, 0, 0);
#pragma unroll
            for (int r = 0; r < 4; ++r)
                RDs[w][(quad * 4 + r) * 132 + nr * 16 + c] = f2bf(acc[r]);
        }

        // gather rel bias, scale, causal mask
        float sc[4][4];
#pragma unroll
        for (int ns = 0; ns < 4; ++ns) {
#pragma unroll
            for (int r = 0; r < 4; ++r) {
                const int r16 = quad * 4 + r;
                const int jc = ns * 16 + c;
                const int dp = w * 16 + r16 - jc + 63;   // in [0,126]
                const float rdv = bf2f(RDs[w][r16 * 132 + dp]);
                const float v = (sAcc[ns][r] + rdv) * 0.125f;
                sc[ns][r] = (j0 + jc > i0 + w * 16 + r16) ? -1e30f : v;
            }
        }
        // online softmax: row stats per reg (rows live in quad's 16 lanes)
        float alpha[4];
#pragma unroll
        for (int r = 0; r < 4; ++r) {
            float m = fmaxf(fmaxf(sc[0][r], sc[1][r]), fmaxf(sc[2][r], sc[3][r]));
#pragma unroll
            for (int off = 1; off < 16; off <<= 1) m = fmaxf(m, __shfl_xor(m, off));
            const float mn = fmaxf(m_i[r], m);
            alpha[r] = __expf(m_i[r] - mn);
            m_i[r] = mn;
        }
        float rs[4] = {0.f, 0.f, 0.f, 0.f};
#pragma unroll
        for (int ns = 0; ns < 4; ++ns) {
#pragma unroll
            for (int r = 0; r < 4; ++r) {
                const float p = __expf(sc[ns][r] - m_i[r]);
                rs[r] += p;
                Ps[w][(quad * 4 + r) * 72 + ns * 16 + c] = f2bf(p);
            }
        }
#pragma unroll
        for (int r = 0; r < 4; ++r) {
#pragma unroll
            for (int off = 1; off < 16; off <<= 1) rs[r] += __shfl_xor(rs[r], off);
            l_i[r] = l_i[r] * alpha[r] + rs[r];
        }
#pragma unroll
        for (int nd = 0; nd < 4; ++nd)
#pragma unroll
            for (int r = 0; r < 4; ++r) oacc[nd][r] *= alpha[r];

        // O += P @ V : P re-read in A-layout from per-wave LDS
        const short8 ap0 = *(const short8*)&Ps[w][c * 72 + 0 * 32 + quad * 8];
        const short8 ap1 = *(const short8*)&Ps[w][c * 72 + 1 * 32 + quad * 8];
#pragma unroll
        for (int nd = 0; nd < 4; ++nd) {
            const short8 bv0 = *(const short8*)&Vs[(nd * 2 + 0) * 512 + lane * 8];
            const short8 bv1 = *(const short8*)&Vs[(nd * 2 + 1) * 512 + lane * 8];
            oacc[nd] = __builtin_amdgcn_mfma_f32_16x16x32_bf16(ap0, bv0, oacc[nd], 0, 0, 0);
            oacc[nd] = __builtin_amdgcn_mfma_f32_16x16x32_bf16(ap1, bv1, oacc[nd], 0, 0, 0);
        }
        __syncthreads();   // staging buffers reused next k-tile
    }

    // epilogue: Yh[b][t][h*64 + d] fp32
#pragma unroll
    for (int r = 0; r < 4; ++r) {
        const float inv = 1.f / l_i[r];
        const int trow = i0 + w * 16 + quad * 4 + r;
        float* yb = Yh + ((size_t)b * TT + trow) * CC + h * HDD;
#pragma unroll
        for (int nd = 0; nd < 4; ++nd)
            yb[nd * 16 + c] = oacc[nd][r] * inv;
    }
}

// ---------------------------------------------------------------------------
// Kernel 4: out = Yh @ w_proj^T + b_proj   (fp32, proven in round 1)
// ---------------------------------------------------------------------------
__global__ __launch_bounds__(256) void gemm_proj_k(
    const float* __restrict__ y, const float* __restrict__ w,
    const float* __restrict__ bias, float* __restrict__ out)
{
    __shared__ float As[16][68];
    __shared__ float Bs[16][68];
    const int tid = threadIdx.x;
    const int bm = blockIdx.y * 64;
    const int bn = blockIdx.x * 64;
    const int tx = tid & 15, ty = tid >> 4;

    float acc[4][4];
#pragma unroll
    for (int i = 0; i < 4; ++i)
#pragma unroll
        for (int j = 0; j < 4; ++j) acc[i][j] = 0.f;

    const int lrow = tid >> 2;
    const int lk = (tid & 3) * 4;
    const float* ya = y + (size_t)(bm + lrow) * 512 + lk;
    const float* wa = w + (size_t)(bn + lrow) * 512 + lk;
    float4 av = *(const float4*)ya;
    float4 bv = *(const float4*)wa;

    for (int k0 = 0; k0 < 512; k0 += 16) {
        __syncthreads();
        As[lk + 0][lrow] = av.x; As[lk + 1][lrow] = av.y;
        As[lk + 2][lrow] = av.z; As[lk + 3][lrow] = av.w;
        Bs[lk + 0][lrow] = bv.x; Bs[lk + 1][lrow] = bv.y;
        Bs[lk + 2][lrow] = bv.z; Bs[lk + 3][lrow] = bv.w;
        __syncthreads();
        if (k0 + 16 < 512) {
            av = *(const float4*)(ya + k0 + 16);
            bv = *(const float4*)(wa + k0 + 16);
        }
#pragma unroll
        for (int kk = 0; kk < 16; ++kk) {
            const float4 a = *(const float4*)&As[kk][ty * 4];
            const float4 b = *(const float4*)&Bs[kk][tx * 4];
            const float am[4] = {a.x, a.y, a.z, a.w};
            const float bb[4] = {b.x, b.y, b.z, b.w};
#pragma unroll
            for (int i = 0; i < 4; ++i)
#pragma unroll
                for (int j = 0; j < 4; ++j) acc[i][j] += am[i] * bb[j];
        }
    }

    const int n = bn + tx * 4;
    const float4 bb4 = *(const float4*)(bias + n);
#pragma unroll
    for (int i = 0; i < 4; ++i) {
        const int m = bm + ty * 4 + i;
        const float4 o = make_float4(acc[i][0] + bb4.x, acc[i][1] + bb4.y,
                                     acc[i][2] + bb4.z, acc[i][3] + bb4.w);
        *(float4*)(out + (size_t)m * 512 + n) = o;
    }
}

// ---------------------------------------------------------------------------
extern "C" void kernel_launch(void* const* d_in, const int* in_sizes, int n_in,
                              void* d_out, int out_size, void* d_ws, size_t ws_size,
                              hipStream_t stream)
{
    const float* x      = (const float*)d_in[0];
    const float* w_attn = (const float*)d_in[1];
    const float* b_attn = (const float*)d_in[2];
    const float* w_proj = (const float*)d_in[3];
    const float* b_proj = (const float*)d_in[4];
    const float* q_g    = (const float*)d_in[5];
    const float* q_b    = (const float*)d_in[6];
    const float* k_g    = (const float*)d_in[7];
    const float* k_b    = (const float*)d_in[8];
    const float* rel    = (const float*)d_in[9];
    float* out = (float*)d_out;

    // workspace: qkbuf f32 16MB | Qh bf16 4MB | Kh 4MB | VT 4MB | Relb 0.5MB | Yh f32 8MB
    float* qkbuf = (float*)d_ws;
    unsigned short* Qh   = (unsigned short*)(qkbuf + (size_t)4096 * 1024);
    unsigned short* Kh   = Qh + (size_t)4096 * 512;
    unsigned short* VT   = Kh + (size_t)4096 * 512;
    unsigned short* Relb = VT + (size_t)4096 * 512;
    float* Yh = (float*)(Relb + (size_t)512 * 512);

    cvt_rel_k<<<256, 256, 0, stream>>>(rel, Relb);
    gemm_qkv_k<<<dim3(24, 32), 256, 0, stream>>>(x, w_attn, b_attn, qkbuf, VT);
    ln_k<<<4096, 256, 0, stream>>>(qkbuf, q_g, q_b, k_g, k_b, Qh, Kh);
    attn_k<<<dim3(8, 8, 8), 256, 0, stream>>>(Qh, Kh, VT, Relb, Yh);
    gemm_proj_k<<<dim3(8, 64), 256, 0, stream>>>(Yh, w_proj, b_proj, out);
}

// Round 3
// 156.700 us; speedup vs baseline: 3.3957x; 1.5267x over previous
//
#include <hip/hip_runtime.h>
#include <hip/hip_bf16.h>
#include <cstddef>

// Shapes (fixed by the problem)
#define BB 8
#define TT 512
#define CC 512
#define NHH 8
#define HDD 64
// M = B*T = 4096, K = 512, N_qkv = 1536

typedef __attribute__((ext_vector_type(8))) short short8;
typedef __attribute__((ext_vector_type(4))) float f32x4;

__device__ __forceinline__ unsigned short f2bf(float f) {
    unsigned u = __float_as_uint(f);
    u += 0x7FFFu + ((u >> 16) & 1u);
    return (unsigned short)(u >> 16);
}
__device__ __forceinline__ float bf2f(unsigned short h) {
    return __uint_as_float(((unsigned)h) << 16);
}

// ---------------------------------------------------------------------------
// Kernel 0: generic fp32 -> bf16 convert (n divisible by 1024)
// ---------------------------------------------------------------------------
__global__ __launch_bounds__(256) void cvt_k(
    const float* __restrict__ in, unsigned short* __restrict__ out)
{
    const int i = (blockIdx.x * 256 + threadIdx.x) * 4;
    const float4 v = *(const float4*)(in + i);
    unsigned short tmp[4] = {f2bf(v.x), f2bf(v.y), f2bf(v.z), f2bf(v.w)};
    *(uint2*)(out + i) = *(const uint2*)tmp;
}

// ---------------------------------------------------------------------------
// Kernel 1: QKV GEMM via MFMA.  C[m][n] = Xb[m][:] . Wb[n][:] + bias[n]
//   Tile 128x128, BK=64, 256 thr = 4 waves (2x2 of 64x64).
//   Fragment-order LDS staging (chunk = 16 rows x 32 cols = 1KB; lane L's 16B
//   at chunkbase + L*16 holds Mat[16*c16+(L&15)][kk*32+(L>>4)*8 ..+8]).
//   q/k (bn<1024) -> qkbuf fp32 [4096][1024]; v -> in-LDS transpose -> VT bf16
//   [b][h][d][t].
// ---------------------------------------------------------------------------
__global__ __launch_bounds__(256, 2) void gemm_qkv_mfma(
    const unsigned short* __restrict__ Xb, const unsigned short* __restrict__ Wb,
    const float* __restrict__ bias, float* __restrict__ qkbuf,
    unsigned short* __restrict__ VT)
{
    // staging: A chunks 0..15 (16KB), B chunks 16..31 (16KB);
    // aliased by v-transpose buffer 128 cols x 136 (pad) shorts = 34816 B.
    __shared__ __align__(16) unsigned short lds[128 * 136];

    const int tid = threadIdx.x;
    const int w = tid >> 6, lane = tid & 63;
    const int c = lane & 15, quad = lane >> 4;
    const int wm = w >> 1, wn = w & 1;
    const int bm = blockIdx.y * 128, bn = blockIdx.x * 128;

    // per-thread staging source pointers: wave w stages chunks w*8 .. w*8+7
    const unsigned short* pp[8];
#pragma unroll
    for (int l = 0; l < 8; ++l) {
        const int ci = w * 8 + l;
        if (ci < 16) {
            const int m16 = ci >> 1, kk = ci & 1;
            pp[l] = Xb + (size_t)(bm + m16 * 16 + c) * 512 + kk * 32 + quad * 8;
        } else {
            const int cb = ci - 16, n16 = cb >> 1, kk = cb & 1;
            pp[l] = Wb + (size_t)(bn + n16 * 16 + c) * 512 + kk * 32 + quad * 8;
        }
    }

    f32x4 acc[4][4];
#pragma unroll
    for (int i = 0; i < 4; ++i)
#pragma unroll
        for (int j = 0; j < 4; ++j) acc[i][j] = (f32x4){0.f, 0.f, 0.f, 0.f};

    short8 pre[8];
#pragma unroll
    for (int l = 0; l < 8; ++l) pre[l] = *(const short8*)pp[l];

    for (int k0 = 0; k0 < 512; k0 += 64) {
        __syncthreads();
#pragma unroll
        for (int l = 0; l < 8; ++l)
            *(short8*)&lds[(w * 8 + l) * 512 + lane * 8] = pre[l];
        __syncthreads();
        if (k0 + 64 < 512) {
#pragma unroll
            for (int l = 0; l < 8; ++l)
                pre[l] = *(const short8*)(pp[l] + k0 + 64);
        }
#pragma unroll
        for (int kk = 0; kk < 2; ++kk) {
            short8 af[4], bfr[4];
#pragma unroll
            for (int i = 0; i < 4; ++i)
                af[i] = *(const short8*)&lds[((wm * 4 + i) * 2 + kk) * 512 + lane * 8];
#pragma unroll
            for (int j = 0; j < 4; ++j)
                bfr[j] = *(const short8*)&lds[(16 + (wn * 4 + j) * 2 + kk) * 512 + lane * 8];
#pragma unroll
            for (int i = 0; i < 4; ++i)
#pragma unroll
                for (int j = 0; j < 4; ++j)
                    acc[i][j] = __builtin_amdgcn_mfma_f32_16x16x32_bf16(
                        af[i], bfr[j], acc[i][j], 0, 0, 0);
        }
    }

    float bj[4];
#pragma unroll
    for (int j = 0; j < 4; ++j) bj[j] = bias[bn + wn * 64 + j * 16 + c];

    if (bn < 1024) {
        // q/k: fp32 store, row-major [m][1024]
#pragma unroll
        for (int i = 0; i < 4; ++i)
#pragma unroll
            for (int j = 0; j < 4; ++j) {
                const int n = bn + wn * 64 + j * 16 + c;
#pragma unroll
                for (int r = 0; r < 4; ++r) {
                    const int m = bm + wm * 64 + i * 16 + quad * 4 + r;
                    qkbuf[(size_t)m * 1024 + n] = acc[i][j][r] + bj[j];
                }
            }
    } else {
        // v: bias + bf16, transpose in LDS -> VT[b][h][d][t]
        __syncthreads();   // staging LDS dead; reuse as [col(hd)][row(t)] stride 136
#pragma unroll
        for (int i = 0; i < 4; ++i)
#pragma unroll
            for (int j = 0; j < 4; ++j) {
                const int col = wn * 64 + j * 16 + c;
                const int row0 = wm * 64 + i * 16 + quad * 4;
                unsigned short t4[4];
#pragma unroll
                for (int r = 0; r < 4; ++r) t4[r] = f2bf(acc[i][j][r] + bj[j]);
                *(uint2*)&lds[col * 136 + row0] = *(const uint2*)t4;
            }
        __syncthreads();
        const int bi = bm >> 9, tb = bm & 511;
        const int hd0 = bn - 1024;
#pragma unroll
        for (int l = 0; l < 8; ++l) {
            const int idx = l * 256 + tid;
            const int col = idx >> 4, grp = idx & 15;
            const short8 v = *(const short8*)&lds[col * 136 + grp * 8];
            const int hd = hd0 + col, h = hd >> 6, d = hd & 63;
            *(short8*)(VT + ((size_t)(bi * NHH + h) * HDD + d) * TT + tb + grp * 8) = v;
        }
    }
}

// ---------------------------------------------------------------------------
// Kernel 2: LayerNorm over C=512 on q and k; outputs bf16 head-major
// ---------------------------------------------------------------------------
__global__ __launch_bounds__(256) void ln_k(
    const float* __restrict__ qkbuf,
    const float* __restrict__ qg, const float* __restrict__ qb,
    const float* __restrict__ kg, const float* __restrict__ kb,
    unsigned short* __restrict__ Qh, unsigned short* __restrict__ Kh)
{
    const int row = blockIdx.x;
    const int bi = row >> 9, t = row & 511;
    const float* base = qkbuf + (size_t)row * 1024;
    const int tid = threadIdx.x;
    __shared__ float red[8];
    __shared__ float stat[2];

#pragma unroll
    for (int sstr = 0; sstr < 2; ++sstr) {
        const float* p = base + sstr * 512;
        const float* gam = sstr ? kg : qg;
        const float* bet = sstr ? kb : qb;
        unsigned short* outp = sstr ? Kh : Qh;
        const float v0 = p[tid];
        const float v1 = p[tid + 256];
        float sum = v0 + v1;
        float sq = v0 * v0 + v1 * v1;
#pragma unroll
        for (int off = 32; off > 0; off >>= 1) {
            sum += __shfl_down(sum, off);
            sq += __shfl_down(sq, off);
        }
        const int lane = tid & 63, wv = tid >> 6;
        if (lane == 0) { red[wv * 2] = sum; red[wv * 2 + 1] = sq; }
        __syncthreads();
        if (tid == 0) {
            const float ts = red[0] + red[2] + red[4] + red[6];
            const float tq = red[1] + red[3] + red[5] + red[7];
            const float mu = ts * (1.f / 512.f);
            const float var = tq * (1.f / 512.f) - mu * mu;
            stat[0] = mu;
            stat[1] = rsqrtf(var + 1e-5f);
        }
        __syncthreads();
        const float mu = stat[0], rsg = stat[1];
        const float o0 = (v0 - mu) * rsg * gam[tid] + bet[tid];
        const float o1 = (v1 - mu) * rsg * gam[tid + 256] + bet[tid + 256];
        const int c0 = tid, c1 = tid + 256;
        outp[((size_t)(bi * NHH + (c0 >> 6)) * TT + t) * HDD + (c0 & 63)] = f2bf(o0);
        outp[((size_t)(bi * NHH + (c1 >> 6)) * TT + t) * HDD + (c1 & 63)] = f2bf(o1);
        __syncthreads();
    }
}

// ---------------------------------------------------------------------------
// Kernel 3: MFMA flash attention with relative-position bias (proven in R2).
//   Epilogue now writes bf16 Yb [4096][512] for the MFMA proj GEMM.
// ---------------------------------------------------------------------------
__global__ __launch_bounds__(256, 2) void attn_k(
    const unsigned short* __restrict__ Qh, const unsigned short* __restrict__ Kh,
    const unsigned short* __restrict__ VT, const unsigned short* __restrict__ Relb,
    unsigned short* __restrict__ Yb)
{
    __shared__ __align__(16) unsigned short Qs[8 * 512];
    __shared__ __align__(16) unsigned short Ks[8 * 512];
    __shared__ __align__(16) unsigned short Vs[8 * 512];
    __shared__ __align__(16) unsigned short Rels[16 * 512];
    __shared__ __align__(16) unsigned short Ps[4][16 * 72];
    __shared__ __align__(16) unsigned short RDs[4][16 * 132];

    const int tid = threadIdx.x;
    const int w = tid >> 6;
    const int lane = tid & 63;
    const int c = lane & 15;
    const int quad = lane >> 4;
    const int qt = blockIdx.x, h = blockIdx.y, b = blockIdx.z;
    const int i0 = qt * 64;

    const unsigned short* Qbase = Qh + (size_t)(b * NHH + h) * TT * HDD;
    const unsigned short* Kbase = Kh + (size_t)(b * NHH + h) * TT * HDD;
    const unsigned short* Vbase = VT + (size_t)(b * NHH + h) * HDD * TT;
    const unsigned short* Rbase = Relb + h * HDD;

#pragma unroll
    for (int kk = 0; kk < 2; ++kk) {
        const unsigned short* gp =
            Qbase + (size_t)(i0 + w * 16 + c) * HDD + kk * 32 + quad * 8;
        *(short8*)&Qs[(w * 2 + kk) * 512 + lane * 8] = *(const short8*)gp;
    }

    f32x4 oacc[4];
    float m_i[4], l_i[4];
#pragma unroll
    for (int r = 0; r < 4; ++r) { m_i[r] = -1e30f; l_i[r] = 0.f; }
#pragma unroll
    for (int nd = 0; nd < 4; ++nd) oacc[nd] = (f32x4){0.f, 0.f, 0.f, 0.f};

    short8 aq0, aq1;

    for (int jt = 0; jt <= qt; ++jt) {
        const int j0 = jt * 64;
#pragma unroll
        for (int kk = 0; kk < 2; ++kk) {
            const unsigned short* gp =
                Kbase + (size_t)(j0 + w * 16 + c) * HDD + kk * 32 + quad * 8;
            *(short8*)&Ks[(w * 2 + kk) * 512 + lane * 8] = *(const short8*)gp;
        }
#pragma unroll
        for (int js = 0; js < 2; ++js) {
            const unsigned short* gp =
                Vbase + (size_t)(w * 16 + c) * TT + j0 + js * 32 + quad * 8;
            *(short8*)&Vs[(w * 2 + js) * 512 + lane * 8] = *(const short8*)gp;
        }
        const int mbase = i0 - j0 - 63;
#pragma unroll
        for (int sb = 0; sb < 2; ++sb) {
#pragma unroll
            for (int kk = 0; kk < 2; ++kk) {
                const int n16 = w * 2 + sb;
                int mrow = mbase + n16 * 16 + c;
                mrow = mrow < 0 ? 0 : (mrow > 511 ? 511 : mrow);
                const unsigned short* gp =
                    Rbase + (size_t)mrow * CC + kk * 32 + quad * 8;
                *(short8*)&Rels[(n16 * 2 + kk) * 512 + lane * 8] = *(const short8*)gp;
            }
        }
        __syncthreads();

        if (jt == 0) {
            aq0 = *(const short8*)&Qs[(w * 2 + 0) * 512 + lane * 8];
            aq1 = *(const short8*)&Qs[(w * 2 + 1) * 512 + lane * 8];
        }

        f32x4 sAcc[4];
#pragma unroll
        for (int ns = 0; ns < 4; ++ns) {
            const short8 bk0 = *(const short8*)&Ks[(ns * 2 + 0) * 512 + lane * 8];
            const short8 bk1 = *(const short8*)&Ks[(ns * 2 + 1) * 512 + lane * 8];
            f32x4 a2 = (f32x4){0.f, 0.f, 0.f, 0.f};
            a2 = __builtin_amdgcn_mfma_f32_16x16x32_bf16(aq0, bk0, a2, 0, 0, 0);
            a2 = __builtin_amdgcn_mfma_f32_16x16x32_bf16(aq1, bk1, a2, 0, 0, 0);
            sAcc[ns] = a2;
        }
#pragma unroll
        for (int nr = 0; nr < 8; ++nr) {
            const short8 br0 = *(const short8*)&Rels[(nr * 2 + 0) * 512 + lane * 8];
            const short8 br1 = *(const short8*)&Rels[(nr * 2 + 1) * 512 + lane * 8];
            f32x4 a2 = (f32x4){0.f, 0.f, 0.f, 0.f};
            a2 = __builtin_amdgcn_mfma_f32_16x16x32_bf16(aq0, br0, a2, 0, 0, 0);
            a2 = __builtin_amdgcn_mfma_f32_16x16x32_bf16(aq1, br1, a2, 0, 0, 0);
#pragma unroll
            for (int r = 0; r < 4; ++r)
                RDs[w][(quad * 4 + r) * 132 + nr * 16 + c] = f2bf(a2[r]);
        }

        float sc[4][4];
#pragma unroll
        for (int ns = 0; ns < 4; ++ns) {
#pragma unroll
            for (int r = 0; r < 4; ++r) {
                const int r16 = quad * 4 + r;
                const int jc = ns * 16 + c;
                const int dp = w * 16 + r16 - jc + 63;
                const float rdv = bf2f(RDs[w][r16 * 132 + dp]);
                const float v = (sAcc[ns][r] + rdv) * 0.125f;
                sc[ns][r] = (j0 + jc > i0 + w * 16 + r16) ? -1e30f : v;
            }
        }
        float alpha[4];
#pragma unroll
        for (int r = 0; r < 4; ++r) {
            float m = fmaxf(fmaxf(sc[0][r], sc[1][r]), fmaxf(sc[2][r], sc[3][r]));
#pragma unroll
            for (int off = 1; off < 16; off <<= 1) m = fmaxf(m, __shfl_xor(m, off));
            const float mn = fmaxf(m_i[r], m);
            alpha[r] = __expf(m_i[r] - mn);
            m_i[r] = mn;
        }
        float rs[4] = {0.f, 0.f, 0.f, 0.f};
#pragma unroll
        for (int ns = 0; ns < 4; ++ns) {
#pragma unroll
            for (int r = 0; r < 4; ++r) {
                const float p = __expf(sc[ns][r] - m_i[r]);
                rs[r] += p;
                Ps[w][(quad * 4 + r) * 72 + ns * 16 + c] = f2bf(p);
            }
        }
#pragma unroll
        for (int r = 0; r < 4; ++r) {
#pragma unroll
            for (int off = 1; off < 16; off <<= 1) rs[r] += __shfl_xor(rs[r], off);
            l_i[r] = l_i[r] * alpha[r] + rs[r];
        }
#pragma unroll
        for (int nd = 0; nd < 4; ++nd)
#pragma unroll
            for (int r = 0; r < 4; ++r) oacc[nd][r] *= alpha[r];

        const short8 ap0 = *(const short8*)&Ps[w][c * 72 + 0 * 32 + quad * 8];
        const short8 ap1 = *(const short8*)&Ps[w][c * 72 + 1 * 32 + quad * 8];
#pragma unroll
        for (int nd = 0; nd < 4; ++nd) {
            const short8 bv0 = *(const short8*)&Vs[(nd * 2 + 0) * 512 + lane * 8];
            const short8 bv1 = *(const short8*)&Vs[(nd * 2 + 1) * 512 + lane * 8];
            oacc[nd] = __builtin_amdgcn_mfma_f32_16x16x32_bf16(ap0, bv0, oacc[nd], 0, 0, 0);
            oacc[nd] = __builtin_amdgcn_mfma_f32_16x16x32_bf16(ap1, bv1, oacc[nd], 0, 0, 0);
        }
        __syncthreads();
    }

    // epilogue: Yb[b][t][h*64 + d] bf16
#pragma unroll
    for (int r = 0; r < 4; ++r) {
        const float inv = 1.f / l_i[r];
        const int trow = i0 + w * 16 + quad * 4 + r;
        unsigned short* yb = Yb + ((size_t)b * TT + trow) * CC + h * HDD;
#pragma unroll
        for (int nd = 0; nd < 4; ++nd)
            yb[nd * 16 + c] = f2bf(oacc[nd][r] * inv);
    }
}

// ---------------------------------------------------------------------------
// Kernel 4: out = Yb @ Wp^T + b_proj via MFMA. M=4096, N=512, K=512.
//   Tile 64x128, BK=64, 4 waves (2x2 of 32x64). 256 blocks.
// ---------------------------------------------------------------------------
__global__ __launch_bounds__(256, 2) void gemm_proj_mfma(
    const unsigned short* __restrict__ Yb, const unsigned short* __restrict__ Wp,
    const float* __restrict__ bias, float* __restrict__ out)
{
    __shared__ __align__(16) unsigned short lds[24 * 512];  // A chunks 0..7, B 8..23

    const int tid = threadIdx.x;
    const int w = tid >> 6, lane = tid & 63;
    const int c = lane & 15, quad = lane >> 4;
    const int wm = w >> 1, wn = w & 1;
    const int bm = blockIdx.y * 64, bn = blockIdx.x * 128;

    const unsigned short* pp[6];
#pragma unroll
    for (int l = 0; l < 6; ++l) {
        const int ci = w * 6 + l;
        if (ci < 8) {
            const int m16 = ci >> 1, kk = ci & 1;
            pp[l] = Yb + (size_t)(bm + m16 * 16 + c) * 512 + kk * 32 + quad * 8;
        } else {
            const int cb = ci - 8, n16 = cb >> 1, kk = cb & 1;
            pp[l] = Wp + (size_t)(bn + n16 * 16 + c) * 512 + kk * 32 + quad * 8;
        }
    }

    f32x4 acc[2][4];
#pragma unroll
    for (int i = 0; i < 2; ++i)
#pragma unroll
        for (int j = 0; j < 4; ++j) acc[i][j] = (f32x4){0.f, 0.f, 0.f, 0.f};

    short8 pre[6];
#pragma unroll
    for (int l = 0; l < 6; ++l) pre[l] = *(const short8*)pp[l];

    for (int k0 = 0; k0 < 512; k0 += 64) {
        __syncthreads();
#pragma unroll
        for (int l = 0; l < 6; ++l)
            *(short8*)&lds[(w * 6 + l) * 512 + lane * 8] = pre[l];
        __syncthreads();
        if (k0 + 64 < 512) {
#pragma unroll
            for (int l = 0; l < 6; ++l)
                pre[l] = *(const short8*)(pp[l] + k0 + 64);
        }
#pragma unroll
        for (int kk = 0; kk < 2; ++kk) {
            short8 af[2], bfr[4];
#pragma unroll
            for (int i = 0; i < 2; ++i)
                af[i] = *(const short8*)&lds[((wm * 2 + i) * 2 + kk) * 512 + lane * 8];
#pragma unroll
            for (int j = 0; j < 4; ++j)
                bfr[j] = *(const short8*)&lds[(8 + (wn * 4 + j) * 2 + kk) * 512 + lane * 8];
#pragma unroll
            for (int i = 0; i < 2; ++i)
#pragma unroll
                for (int j = 0; j < 4; ++j)
                    acc[i][j] = __builtin_amdgcn_mfma_f32_16x16x32_bf16(
                        af[i], bfr[j], acc[i][j], 0, 0, 0);
        }
    }

#pragma unroll
    for (int j = 0; j < 4; ++j) {
        const int n = bn + wn * 64 + j * 16 + c;
        const float bj = bias[n];
#pragma unroll
        for (int i = 0; i < 2; ++i)
#pragma unroll
            for (int r = 0; r < 4; ++r) {
                const int m = bm + wm * 32 + i * 16 + quad * 4 + r;
                out[(size_t)m * 512 + n] = acc[i][j][r] + bj;
            }
    }
}

// ---------------------------------------------------------------------------
extern "C" void kernel_launch(void* const* d_in, const int* in_sizes, int n_in,
                              void* d_out, int out_size, void* d_ws, size_t ws_size,
                              hipStream_t stream)
{
    const float* x      = (const float*)d_in[0];
    const float* w_attn = (const float*)d_in[1];
    const float* b_attn = (const float*)d_in[2];
    const float* w_proj = (const float*)d_in[3];
    const float* b_proj = (const float*)d_in[4];
    const float* q_g    = (const float*)d_in[5];
    const float* q_b    = (const float*)d_in[6];
    const float* k_g    = (const float*)d_in[7];
    const float* k_b    = (const float*)d_in[8];
    const float* rel    = (const float*)d_in[9];
    float* out = (float*)d_out;

    // workspace (34.5 MB): qkbuf f32 16MB | Qh 4 | Kh 4 | VT 4 | Relb 0.5 |
    //                      Xb 4 | Wqb 1.5 | Wpb 0.5   (bf16 MB)
    // Yb (bf16 4MB) aliases qkbuf, which is dead after ln_k.
    float* qkbuf = (float*)d_ws;
    unsigned short* Qh   = (unsigned short*)(qkbuf + (size_t)4096 * 1024);
    unsigned short* Kh   = Qh + (size_t)4096 * 512;
    unsigned short* VT   = Kh + (size_t)4096 * 512;
    unsigned short* Relb = VT + (size_t)4096 * 512;
    unsigned short* Xb   = Relb + (size_t)512 * 512;
    unsigned short* Wqb  = Xb + (size_t)4096 * 512;
    unsigned short* Wpb  = Wqb + (size_t)1536 * 512;
    unsigned short* Yb   = (unsigned short*)qkbuf;

    cvt_k<<<2048, 256, 0, stream>>>(x, Xb);
    cvt_k<<<768, 256, 0, stream>>>(w_attn, Wqb);
    cvt_k<<<256, 256, 0, stream>>>(w_proj, Wpb);
    cvt_k<<<256, 256, 0, stream>>>(rel, Relb);
    gemm_qkv_mfma<<<dim3(12, 32), 256, 0, stream>>>(Xb, Wqb, b_attn, qkbuf, VT);
    ln_k<<<4096, 256, 0, stream>>>(qkbuf, q_g, q_b, k_g, k_b, Qh, Kh);
    attn_k<<<dim3(8, 8, 8), 256, 0, stream>>>(Qh, Kh, VT, Relb, Yb);
    gemm_proj_mfma<<<dim3(4, 64), 256, 0, stream>>>(Yb, Wpb, b_proj, out);
}

// Round 4
// 149.626 us; speedup vs baseline: 3.5562x; 1.0473x over previous
//
#include <hip/hip_runtime.h>
#include <hip/hip_bf16.h>
#include <cstddef>

// Shapes (fixed by the problem)
#define BB 8
#define TT 512
#define CC 512
#define NHH 8
#define HDD 64
// M = B*T = 4096, K = 512, N_qkv = 1536

typedef __attribute__((ext_vector_type(8))) short short8;
typedef __attribute__((ext_vector_type(4))) float f32x4;

__device__ __forceinline__ unsigned short f2bf(float f) {
    unsigned u = __float_as_uint(f);
    u += 0x7FFFu + ((u >> 16) & 1u);
    return (unsigned short)(u >> 16);
}
__device__ __forceinline__ float bf2f(unsigned short h) {
    return __uint_as_float(((unsigned)h) << 16);
}

// ---------------------------------------------------------------------------
// Kernel 0: fused fp32 -> bf16 convert for x / w_attn / w_proj / rel.
//   Segments by blockIdx: [0,2048) x, [2048,2816) w_attn, [2816,3072) w_proj,
//   [3072,3328) rel. 1024 elems per block.
// ---------------------------------------------------------------------------
__global__ __launch_bounds__(256) void cvt_all_k(
    const float* __restrict__ x, const float* __restrict__ wa,
    const float* __restrict__ wp, const float* __restrict__ rel,
    unsigned short* __restrict__ Xb, unsigned short* __restrict__ Wqb,
    unsigned short* __restrict__ Wpb, unsigned short* __restrict__ Relb)
{
    const int bidx = blockIdx.x;
    const float* in;
    unsigned short* out;
    int base;
    if (bidx < 2048)      { in = x;   out = Xb;   base = bidx; }
    else if (bidx < 2816) { in = wa;  out = Wqb;  base = bidx - 2048; }
    else if (bidx < 3072) { in = wp;  out = Wpb;  base = bidx - 2816; }
    else                  { in = rel; out = Relb; base = bidx - 3072; }
    const int i = base * 1024 + threadIdx.x * 4;
    const float4 v = *(const float4*)(in + i);
    unsigned short tmp[4] = {f2bf(v.x), f2bf(v.y), f2bf(v.z), f2bf(v.w)};
    *(uint2*)(out + i) = *(const uint2*)tmp;
}

// ---------------------------------------------------------------------------
// Kernel 1: QKV GEMM via MFMA (proven R3).  C[m][n] = Xb[m][:] . Wb[n][:] + b
//   q/k -> qkbuf fp32 [4096][1024]; v -> in-LDS transpose -> VT bf16 [b][h][d][t]
// ---------------------------------------------------------------------------
__global__ __launch_bounds__(256, 2) void gemm_qkv_mfma(
    const unsigned short* __restrict__ Xb, const unsigned short* __restrict__ Wb,
    const float* __restrict__ bias, float* __restrict__ qkbuf,
    unsigned short* __restrict__ VT)
{
    __shared__ __align__(16) unsigned short lds[128 * 136];

    const int tid = threadIdx.x;
    const int w = tid >> 6, lane = tid & 63;
    const int c = lane & 15, quad = lane >> 4;
    const int wm = w >> 1, wn = w & 1;
    const int bm = blockIdx.y * 128, bn = blockIdx.x * 128;

    const unsigned short* pp[8];
#pragma unroll
    for (int l = 0; l < 8; ++l) {
        const int ci = w * 8 + l;
        if (ci < 16) {
            const int m16 = ci >> 1, kk = ci & 1;
            pp[l] = Xb + (size_t)(bm + m16 * 16 + c) * 512 + kk * 32 + quad * 8;
        } else {
            const int cb = ci - 16, n16 = cb >> 1, kk = cb & 1;
            pp[l] = Wb + (size_t)(bn + n16 * 16 + c) * 512 + kk * 32 + quad * 8;
        }
    }

    f32x4 acc[4][4];
#pragma unroll
    for (int i = 0; i < 4; ++i)
#pragma unroll
        for (int j = 0; j < 4; ++j) acc[i][j] = (f32x4){0.f, 0.f, 0.f, 0.f};

    short8 pre[8];
#pragma unroll
    for (int l = 0; l < 8; ++l) pre[l] = *(const short8*)pp[l];

    for (int k0 = 0; k0 < 512; k0 += 64) {
        __syncthreads();
#pragma unroll
        for (int l = 0; l < 8; ++l)
            *(short8*)&lds[(w * 8 + l) * 512 + lane * 8] = pre[l];
        __syncthreads();
        if (k0 + 64 < 512) {
#pragma unroll
            for (int l = 0; l < 8; ++l)
                pre[l] = *(const short8*)(pp[l] + k0 + 64);
        }
#pragma unroll
        for (int kk = 0; kk < 2; ++kk) {
            short8 af[4], bfr[4];
#pragma unroll
            for (int i = 0; i < 4; ++i)
                af[i] = *(const short8*)&lds[((wm * 4 + i) * 2 + kk) * 512 + lane * 8];
#pragma unroll
            for (int j = 0; j < 4; ++j)
                bfr[j] = *(const short8*)&lds[(16 + (wn * 4 + j) * 2 + kk) * 512 + lane * 8];
#pragma unroll
            for (int i = 0; i < 4; ++i)
#pragma unroll
                for (int j = 0; j < 4; ++j)
                    acc[i][j] = __builtin_amdgcn_mfma_f32_16x16x32_bf16(
                        af[i], bfr[j], acc[i][j], 0, 0, 0);
        }
    }

    float bj[4];
#pragma unroll
    for (int j = 0; j < 4; ++j) bj[j] = bias[bn + wn * 64 + j * 16 + c];

    if (bn < 1024) {
#pragma unroll
        for (int i = 0; i < 4; ++i)
#pragma unroll
            for (int j = 0; j < 4; ++j) {
                const int n = bn + wn * 64 + j * 16 + c;
#pragma unroll
                for (int r = 0; r < 4; ++r) {
                    const int m = bm + wm * 64 + i * 16 + quad * 4 + r;
                    qkbuf[(size_t)m * 1024 + n] = acc[i][j][r] + bj[j];
                }
            }
    } else {
        __syncthreads();
#pragma unroll
        for (int i = 0; i < 4; ++i)
#pragma unroll
            for (int j = 0; j < 4; ++j) {
                const int col = wn * 64 + j * 16 + c;
                const int row0 = wm * 64 + i * 16 + quad * 4;
                unsigned short t4[4];
#pragma unroll
                for (int r = 0; r < 4; ++r) t4[r] = f2bf(acc[i][j][r] + bj[j]);
                *(uint2*)&lds[col * 136 + row0] = *(const uint2*)t4;
            }
        __syncthreads();
        const int bi = bm >> 9, tb = bm & 511;
        const int hd0 = bn - 1024;
#pragma unroll
        for (int l = 0; l < 8; ++l) {
            const int idx = l * 256 + tid;
            const int col = idx >> 4, grp = idx & 15;
            const short8 v = *(const short8*)&lds[col * 136 + grp * 8];
            const int hd = hd0 + col, h = hd >> 6, d = hd & 63;
            *(short8*)(VT + ((size_t)(bi * NHH + h) * HDD + d) * TT + tb + grp * 8) = v;
        }
    }
}

// ---------------------------------------------------------------------------
// Kernel 2: LayerNorm over C=512 on q and k; outputs bf16 head-major
// ---------------------------------------------------------------------------
__global__ __launch_bounds__(256) void ln_k(
    const float* __restrict__ qkbuf,
    const float* __restrict__ qg, const float* __restrict__ qb,
    const float* __restrict__ kg, const float* __restrict__ kb,
    unsigned short* __restrict__ Qh, unsigned short* __restrict__ Kh)
{
    const int row = blockIdx.x;
    const int bi = row >> 9, t = row & 511;
    const float* base = qkbuf + (size_t)row * 1024;
    const int tid = threadIdx.x;
    __shared__ float red[8];
    __shared__ float stat[2];

#pragma unroll
    for (int sstr = 0; sstr < 2; ++sstr) {
        const float* p = base + sstr * 512;
        const float* gam = sstr ? kg : qg;
        const float* bet = sstr ? kb : qb;
        unsigned short* outp = sstr ? Kh : Qh;
        const float v0 = p[tid];
        const float v1 = p[tid + 256];
        float sum = v0 + v1;
        float sq = v0 * v0 + v1 * v1;
#pragma unroll
        for (int off = 32; off > 0; off >>= 1) {
            sum += __shfl_down(sum, off);
            sq += __shfl_down(sq, off);
        }
        const int lane = tid & 63, wv = tid >> 6;
        if (lane == 0) { red[wv * 2] = sum; red[wv * 2 + 1] = sq; }
        __syncthreads();
        if (tid == 0) {
            const float ts = red[0] + red[2] + red[4] + red[6];
            const float tq = red[1] + red[3] + red[5] + red[7];
            const float mu = ts * (1.f / 512.f);
            const float var = tq * (1.f / 512.f) - mu * mu;
            stat[0] = mu;
            stat[1] = rsqrtf(var + 1e-5f);
        }
        __syncthreads();
        const float mu = stat[0], rsg = stat[1];
        const float o0 = (v0 - mu) * rsg * gam[tid] + bet[tid];
        const float o1 = (v1 - mu) * rsg * gam[tid + 256] + bet[tid + 256];
        const int c0 = tid, c1 = tid + 256;
        outp[((size_t)(bi * NHH + (c0 >> 6)) * TT + t) * HDD + (c0 & 63)] = f2bf(o0);
        outp[((size_t)(bi * NHH + (c1 >> 6)) * TT + t) * HDD + (c1 & 63)] = f2bf(o1);
        __syncthreads();
    }
}

// ---------------------------------------------------------------------------
// Kernel 3: MFMA flash attention with relative-position bias.
//   R4 change: RD = Q . rel[delta] is held in a per-wave circular LDS buffer
//   indexed by (delta & 127). The rel window shifts by exactly 64 deltas per
//   jt step, so after the first iteration only 4 of 8 RD subtiles (the new
//   deltas [mbase, mbase+63]) are computed; the rest are reused.
//   Collision-free: new cols (m-64..m-1 mod 128) vs live (m..m+63 mod 128).
// ---------------------------------------------------------------------------
#define RD_BODY(nr_)                                                            \
    {                                                                           \
        const short8 br0 = *(const short8*)&Rels[((nr_) * 2 + 0) * 512 + lane * 8]; \
        const short8 br1 = *(const short8*)&Rels[((nr_) * 2 + 1) * 512 + lane * 8]; \
        f32x4 a2 = (f32x4){0.f, 0.f, 0.f, 0.f};                                 \
        a2 = __builtin_amdgcn_mfma_f32_16x16x32_bf16(aq0, br0, a2, 0, 0, 0);    \
        a2 = __builtin_amdgcn_mfma_f32_16x16x32_bf16(aq1, br1, a2, 0, 0, 0);    \
        const int colw = (mbase + (nr_) * 16 + c) & 127;                        \
        _Pragma("unroll")                                                       \
        for (int r = 0; r < 4; ++r)                                             \
            RDs[w][(quad * 4 + r) * 132 + colw] = f2bf(a2[r]);                  \
    }

__global__ __launch_bounds__(256, 2) void attn_k(
    const unsigned short* __restrict__ Qh, const unsigned short* __restrict__ Kh,
    const unsigned short* __restrict__ VT, const unsigned short* __restrict__ Relb,
    unsigned short* __restrict__ Yb)
{
    __shared__ __align__(16) unsigned short Qs[8 * 512];
    __shared__ __align__(16) unsigned short Ks[8 * 512];
    __shared__ __align__(16) unsigned short Vs[8 * 512];
    __shared__ __align__(16) unsigned short Rels[16 * 512];
    __shared__ __align__(16) unsigned short Ps[4][16 * 72];
    __shared__ __align__(16) unsigned short RDs[4][16 * 132];  // circular, col = delta&127

    const int tid = threadIdx.x;
    const int w = tid >> 6;
    const int lane = tid & 63;
    const int c = lane & 15;
    const int quad = lane >> 4;
    const int qt = blockIdx.x, h = blockIdx.y, b = blockIdx.z;
    const int i0 = qt * 64;

    const unsigned short* Qbase = Qh + (size_t)(b * NHH + h) * TT * HDD;
    const unsigned short* Kbase = Kh + (size_t)(b * NHH + h) * TT * HDD;
    const unsigned short* Vbase = VT + (size_t)(b * NHH + h) * HDD * TT;
    const unsigned short* Rbase = Relb + h * HDD;

#pragma unroll
    for (int kk = 0; kk < 2; ++kk) {
        const unsigned short* gp =
            Qbase + (size_t)(i0 + w * 16 + c) * HDD + kk * 32 + quad * 8;
        *(short8*)&Qs[(w * 2 + kk) * 512 + lane * 8] = *(const short8*)gp;
    }

    f32x4 oacc[4];
    float m_i[4], l_i[4];
#pragma unroll
    for (int r = 0; r < 4; ++r) { m_i[r] = -1e30f; l_i[r] = 0.f; }
#pragma unroll
    for (int nd = 0; nd < 4; ++nd) oacc[nd] = (f32x4){0.f, 0.f, 0.f, 0.f};

    short8 aq0, aq1;

    for (int jt = 0; jt <= qt; ++jt) {
        const int j0 = jt * 64;
#pragma unroll
        for (int kk = 0; kk < 2; ++kk) {
            const unsigned short* gp =
                Kbase + (size_t)(j0 + w * 16 + c) * HDD + kk * 32 + quad * 8;
            *(short8*)&Ks[(w * 2 + kk) * 512 + lane * 8] = *(const short8*)gp;
        }
#pragma unroll
        for (int js = 0; js < 2; ++js) {
            const unsigned short* gp =
                Vbase + (size_t)(w * 16 + c) * TT + j0 + js * 32 + quad * 8;
            *(short8*)&Vs[(w * 2 + js) * 512 + lane * 8] = *(const short8*)gp;
        }
        // rel window staging: first iter 8 groups (128 deltas), later 4 (64 new)
        const int mbase = i0 - j0 - 63;
        if (jt == 0) {
#pragma unroll
            for (int sb = 0; sb < 2; ++sb) {
#pragma unroll
                for (int kk = 0; kk < 2; ++kk) {
                    const int n16 = w * 2 + sb;
                    int mrow = mbase + n16 * 16 + c;
                    mrow = mrow < 0 ? 0 : (mrow > 511 ? 511 : mrow);
                    *(short8*)&Rels[(n16 * 2 + kk) * 512 + lane * 8] =
                        *(const short8*)(Rbase + (size_t)mrow * CC + kk * 32 + quad * 8);
                }
            }
        } else {
#pragma unroll
            for (int kk = 0; kk < 2; ++kk) {
                int mrow = mbase + w * 16 + c;
                mrow = mrow < 0 ? 0 : (mrow > 511 ? 511 : mrow);
                *(short8*)&Rels[(w * 2 + kk) * 512 + lane * 8] =
                    *(const short8*)(Rbase + (size_t)mrow * CC + kk * 32 + quad * 8);
            }
        }
        __syncthreads();

        if (jt == 0) {
            aq0 = *(const short8*)&Qs[(w * 2 + 0) * 512 + lane * 8];
            aq1 = *(const short8*)&Qs[(w * 2 + 1) * 512 + lane * 8];
        }

        // S = Q @ K^T
        f32x4 sAcc[4];
#pragma unroll
        for (int ns = 0; ns < 4; ++ns) {
            const short8 bk0 = *(const short8*)&Ks[(ns * 2 + 0) * 512 + lane * 8];
            const short8 bk1 = *(const short8*)&Ks[(ns * 2 + 1) * 512 + lane * 8];
            f32x4 a2 = (f32x4){0.f, 0.f, 0.f, 0.f};
            a2 = __builtin_amdgcn_mfma_f32_16x16x32_bf16(aq0, bk0, a2, 0, 0, 0);
            a2 = __builtin_amdgcn_mfma_f32_16x16x32_bf16(aq1, bk1, a2, 0, 0, 0);
            sAcc[ns] = a2;
        }
        // RD: only new delta subtiles
        if (jt == 0) {
#pragma unroll
            for (int nr = 0; nr < 8; ++nr) RD_BODY(nr)
        } else {
#pragma unroll
            for (int nr = 0; nr < 4; ++nr) RD_BODY(nr)
        }

        // gather rel bias (circular col = delta & 127), scale, causal mask
        const int dbase = i0 - j0;
        float sc[4][4];
#pragma unroll
        for (int ns = 0; ns < 4; ++ns) {
#pragma unroll
            for (int r = 0; r < 4; ++r) {
                const int r16 = quad * 4 + r;
                const int jc = ns * 16 + c;
                const int dp = (dbase + w * 16 + r16 - jc) & 127;
                const float rdv = bf2f(RDs[w][r16 * 132 + dp]);
                const float v = (sAcc[ns][r] + rdv) * 0.125f;
                sc[ns][r] = (j0 + jc > i0 + w * 16 + r16) ? -1e30f : v;
            }
        }
        float alpha[4];
#pragma unroll
        for (int r = 0; r < 4; ++r) {
            float m = fmaxf(fmaxf(sc[0][r], sc[1][r]), fmaxf(sc[2][r], sc[3][r]));
#pragma unroll
            for (int off = 1; off < 16; off <<= 1) m = fmaxf(m, __shfl_xor(m, off));
            const float mn = fmaxf(m_i[r], m);
            alpha[r] = __expf(m_i[r] - mn);
            m_i[r] = mn;
        }
        float rs[4] = {0.f, 0.f, 0.f, 0.f};
#pragma unroll
        for (int ns = 0; ns < 4; ++ns) {
#pragma unroll
            for (int r = 0; r < 4; ++r) {
                const float p = __expf(sc[ns][r] - m_i[r]);
                rs[r] += p;
                Ps[w][(quad * 4 + r) * 72 + ns * 16 + c] = f2bf(p);
            }
        }
#pragma unroll
        for (int r = 0; r < 4; ++r) {
#pragma unroll
            for (int off = 1; off < 16; off <<= 1) rs[r] += __shfl_xor(rs[r], off);
            l_i[r] = l_i[r] * alpha[r] + rs[r];
        }
#pragma unroll
        for (int nd = 0; nd < 4; ++nd)
#pragma unroll
            for (int r = 0; r < 4; ++r) oacc[nd][r] *= alpha[r];

        const short8 ap0 = *(const short8*)&Ps[w][c * 72 + 0 * 32 + quad * 8];
        const short8 ap1 = *(const short8*)&Ps[w][c * 72 + 1 * 32 + quad * 8];
#pragma unroll
        for (int nd = 0; nd < 4; ++nd) {
            const short8 bv0 = *(const short8*)&Vs[(nd * 2 + 0) * 512 + lane * 8];
            const short8 bv1 = *(const short8*)&Vs[(nd * 2 + 1) * 512 + lane * 8];
            oacc[nd] = __builtin_amdgcn_mfma_f32_16x16x32_bf16(ap0, bv0, oacc[nd], 0, 0, 0);
            oacc[nd] = __builtin_amdgcn_mfma_f32_16x16x32_bf16(ap1, bv1, oacc[nd], 0, 0, 0);
        }
        __syncthreads();
    }

    // epilogue: Yb[b][t][h*64 + d] bf16
#pragma unroll
    for (int r = 0; r < 4; ++r) {
        const float inv = 1.f / l_i[r];
        const int trow = i0 + w * 16 + quad * 4 + r;
        unsigned short* yb = Yb + ((size_t)b * TT + trow) * CC + h * HDD;
#pragma unroll
        for (int nd = 0; nd < 4; ++nd)
            yb[nd * 16 + c] = f2bf(oacc[nd][r] * inv);
    }
}

// ---------------------------------------------------------------------------
// Kernel 4: out = Yb @ Wp^T + b_proj via MFMA (proven R3).
// ---------------------------------------------------------------------------
__global__ __launch_bounds__(256, 2) void gemm_proj_mfma(
    const unsigned short* __restrict__ Yb, const unsigned short* __restrict__ Wp,
    const float* __restrict__ bias, float* __restrict__ out)
{
    __shared__ __align__(16) unsigned short lds[24 * 512];

    const int tid = threadIdx.x;
    const int w = tid >> 6, lane = tid & 63;
    const int c = lane & 15, quad = lane >> 4;
    const int wm = w >> 1, wn = w & 1;
    const int bm = blockIdx.y * 64, bn = blockIdx.x * 128;

    const unsigned short* pp[6];
#pragma unroll
    for (int l = 0; l < 6; ++l) {
        const int ci = w * 6 + l;
        if (ci < 8) {
            const int m16 = ci >> 1, kk = ci & 1;
            pp[l] = Yb + (size_t)(bm + m16 * 16 + c) * 512 + kk * 32 + quad * 8;
        } else {
            const int cb = ci - 8, n16 = cb >> 1, kk = cb & 1;
            pp[l] = Wp + (size_t)(bn + n16 * 16 + c) * 512 + kk * 32 + quad * 8;
        }
    }

    f32x4 acc[2][4];
#pragma unroll
    for (int i = 0; i < 2; ++i)
#pragma unroll
        for (int j = 0; j < 4; ++j) acc[i][j] = (f32x4){0.f, 0.f, 0.f, 0.f};

    short8 pre[6];
#pragma unroll
    for (int l = 0; l < 6; ++l) pre[l] = *(const short8*)pp[l];

    for (int k0 = 0; k0 < 512; k0 += 64) {
        __syncthreads();
#pragma unroll
        for (int l = 0; l < 6; ++l)
            *(short8*)&lds[(w * 6 + l) * 512 + lane * 8] = pre[l];
        __syncthreads();
        if (k0 + 64 < 512) {
#pragma unroll
            for (int l = 0; l < 6; ++l)
                pre[l] = *(const short8*)(pp[l] + k0 + 64);
        }
#pragma unroll
        for (int kk = 0; kk < 2; ++kk) {
            short8 af[2], bfr[4];
#pragma unroll
            for (int i = 0; i < 2; ++i)
                af[i] = *(const short8*)&lds[((wm * 2 + i) * 2 + kk) * 512 + lane * 8];
#pragma unroll
            for (int j = 0; j < 4; ++j)
                bfr[j] = *(const short8*)&lds[(8 + (wn * 4 + j) * 2 + kk) * 512 + lane * 8];
#pragma unroll
            for (int i = 0; i < 2; ++i)
#pragma unroll
                for (int j = 0; j < 4; ++j)
                    acc[i][j] = __builtin_amdgcn_mfma_f32_16x16x32_bf16(
                        af[i], bfr[j], acc[i][j], 0, 0, 0);
        }
    }

#pragma unroll
    for (int j = 0; j < 4; ++j) {
        const int n = bn + wn * 64 + j * 16 + c;
        const float bj = bias[n];
#pragma unroll
        for (int i = 0; i < 2; ++i)
#pragma unroll
            for (int r = 0; r < 4; ++r) {
                const int m = bm + wm * 32 + i * 16 + quad * 4 + r;
                out[(size_t)m * 512 + n] = acc[i][j][r] + bj;
            }
    }
}

// ---------------------------------------------------------------------------
extern "C" void kernel_launch(void* const* d_in, const int* in_sizes, int n_in,
                              void* d_out, int out_size, void* d_ws, size_t ws_size,
                              hipStream_t stream)
{
    const float* x      = (const float*)d_in[0];
    const float* w_attn = (const float*)d_in[1];
    const float* b_attn = (const float*)d_in[2];
    const float* w_proj = (const float*)d_in[3];
    const float* b_proj = (const float*)d_in[4];
    const float* q_g    = (const float*)d_in[5];
    const float* q_b    = (const float*)d_in[6];
    const float* k_g    = (const float*)d_in[7];
    const float* k_b    = (const float*)d_in[8];
    const float* rel    = (const float*)d_in[9];
    float* out = (float*)d_out;

    // workspace (34.5 MB): qkbuf f32 16MB | Qh 4 | Kh 4 | VT 4 | Relb 0.5 |
    //                      Xb 4 | Wqb 1.5 | Wpb 0.5   (bf16 MB)
    // Yb (bf16 4MB) aliases qkbuf (dead after ln_k).
    float* qkbuf = (float*)d_ws;
    unsigned short* Qh   = (unsigned short*)(qkbuf + (size_t)4096 * 1024);
    unsigned short* Kh   = Qh + (size_t)4096 * 512;
    unsigned short* VT   = Kh + (size_t)4096 * 512;
    unsigned short* Relb = VT + (size_t)4096 * 512;
    unsigned short* Xb   = Relb + (size_t)512 * 512;
    unsigned short* Wqb  = Xb + (size_t)4096 * 512;
    unsigned short* Wpb  = Wqb + (size_t)1536 * 512;
    unsigned short* Yb   = (unsigned short*)qkbuf;

    cvt_all_k<<<3328, 256, 0, stream>>>(x, w_attn, w_proj, rel, Xb, Wqb, Wpb, Relb);
    gemm_qkv_mfma<<<dim3(12, 32), 256, 0, stream>>>(Xb, Wqb, b_attn, qkbuf, VT);
    ln_k<<<4096, 256, 0, stream>>>(qkbuf, q_g, q_b, k_g, k_b, Qh, Kh);
    attn_k<<<dim3(8, 8, 8), 256, 0, stream>>>(Qh, Kh, VT, Relb, Yb);
    gemm_proj_mfma<<<dim3(4, 64), 256, 0, stream>>>(Yb, Wpb, b_proj, out);
}